// Round 4
// baseline (470.748 us; speedup 1.0000x reference)
//
#include <hip/hip_runtime.h>
#include <math.h>

typedef _Float16 half8 __attribute__((ext_vector_type(8)));
typedef _Float16 half4_t __attribute__((ext_vector_type(4)));
typedef float floatx16 __attribute__((ext_vector_type(16)));
typedef float float4_t __attribute__((ext_vector_type(4)));

#define NT 128
#define NB 64

// element index with 8-f16 (16B) unit XOR swizzle inside a 64-f16 (128B) row
__device__ __forceinline__ int eidx(int row, int col) {
  return row * 64 + ((((col >> 3) ^ row) & 7) << 3) + (col & 7);
}

__global__ __launch_bounds__(512, 2)
void qrnn4(const float* __restrict__ data_r, const float* __restrict__ data_i,
           const float* __restrict__ U_r, const float* __restrict__ U_i,
           const float* __restrict__ lam_p, float* __restrict__ out) {
  __shared__ __align__(16) _Float16 Vr[4096], Vi[4096];
  __shared__ __align__(16) _Float16 Tr[4096], Ti[4096];
  __shared__ __align__(16) _Float16 Xr[4096], Xi[4096];
  __shared__ __align__(16) _Float16 Or_[4096], Oi_[4096];
  __shared__ float red[8];

  const int b   = blockIdx.x;
  const int tid = threadIdx.x;
  const int lane = tid & 63;
  const int hi   = lane >> 5;
  const int l31  = lane & 31;
  const int w    = tid >> 6;
  const int grp  = w >> 2;        // 0: real, 1: imag
  const int rblk = (w >> 1) & 1;  // state-row block (stage1 A-row, stage2 B-col)
  const int pblk = w & 1;         // U row block (stage1 B-col, stage2 A-row)

  const float g = 1.0f / (1.0f + expf(-lam_p[0]));

  // U fragments: row = 32*pblk + l31, k = 16*kq + 8*hi + e.
  // Serve as stage1 B-operand (acts as U^T) and stage2 A-operand (acts as U).
  half8 Urh[4], Url[4], Uih[4], Uil[4];
  {
    const int row = 32 * pblk + l31;
    #pragma unroll
    for (int kq = 0; kq < 4; ++kq) {
      const int c0 = 16 * kq + 8 * hi;
      #pragma unroll
      for (int e = 0; e < 8; ++e) {
        const float ur = U_r[row * 64 + c0 + e];
        const float ui = U_i[row * 64 + c0 + e];
        _Float16 h;
        h = (_Float16)ur; Urh[kq][e] = h; Url[kq][e] = (_Float16)((ur - (float)h) * 256.0f);
        h = (_Float16)ui; Uih[kq][e] = h; Uil[kq][e] = (_Float16)((ui - (float)h) * 256.0f);
      }
    }
  }

  // thread state element: h[prow][jcol(j)], jcol(j) = 32*pblk + (j&3) + 8*(j>>2) + 4*hi
  const int prow = 32 * rblk + l31;

  // init: h0_r = I/64, h0_i = 0  (BUG FIX vs R2/R3: imag group must start at 0)
  float rv[16];
  float mloc = 0.0f;
  #pragma unroll
  for (int j = 0; j < 16; ++j) {
    const int jcol = 32 * pblk + (j & 3) + 8 * (j >> 2) + 4 * hi;
    rv[j] = (grp == 0 && prow == jcol) ? (1.0f / 64.0f) : 0.0f;
    mloc = fmaxf(mloc, fabsf(rv[j]));
  }
  #pragma unroll
  for (int d = 32; d >= 1; d >>= 1) mloc = fmaxf(mloc, __shfl_xor(mloc, d, 64));
  if (lane == 0) red[w] = mloc;

  // prologue: x_0 -> X (coalesced f32 loads, f16 staging)
  const int dq = tid >> 3, dr0 = (tid & 7) * 8;
  {
    const size_t xb = (size_t)b * 4096 + (size_t)(dq * 64 + dr0);
    float4_t a0 = *(const float4_t*)(data_r + xb);
    float4_t a1 = *(const float4_t*)(data_r + xb + 4);
    float4_t c0 = *(const float4_t*)(data_i + xb);
    float4_t c1 = *(const float4_t*)(data_i + xb + 4);
    half8 hx, hy;
    #pragma unroll
    for (int e = 0; e < 4; ++e) {
      hx[e] = (_Float16)a0[e]; hx[4 + e] = (_Float16)a1[e];
      hy[e] = (_Float16)c0[e]; hy[4 + e] = (_Float16)c1[e];
    }
    *(half8*)&Xr[eidx(dq, dr0)] = hx;
    *(half8*)&Xi[eidx(dq, dr0)] = hy;
  }
  float Sig = 1.0f;
  __syncthreads();  // red + X published

  for (int s = 0; s < NT; ++s) {
    // ===== MIX: fresh alpha from red (max |rv| of CURRENT state), V/O writes =====
    float alphainv;
    {
      float mm = red[0];
      #pragma unroll
      for (int i = 1; i < 8; ++i) mm = fmaxf(mm, red[i]);
      int E = 0;
      if (mm > 0.0f) frexpf(mm, &E);
      const float alpha = ldexpf(1.0f, -E);  // pins max|alpha*rv| to [0.5,1)
      alphainv = ldexpf(1.0f, E);
      const float ga = g * alpha;
      const float kx = (1.0f - g) * alpha / Sig;
      const _Float16* Xg = grp ? Xi : Xr;
      _Float16* Vg = grp ? Vi : Vr;
      _Float16* Og = grp ? Oi_ : Or_;
      #pragma unroll
      for (int jj = 0; jj < 4; ++jj) {
        const int j0 = 32 * pblk + 8 * jj + 4 * hi;
        half4_t xv = *(const half4_t*)&Xg[eidx(prow, j0)];
        half4_t ov;
        #pragma unroll
        for (int e = 0; e < 4; ++e) {
          const float r = rv[4 * jj + e];
          ov[e] = (_Float16)r;
          const float vv = ga * r + kx * (float)xv[e];
          Vg[eidx(j0 + e, prow)] = (_Float16)vv;   // transpose write: V^T
        }
        *(half4_t*)&Og[eidx(prow, j0)] = ov;       // stage raw rv for out drain
      }
    }
    __syncthreads();  // bar1: V, O published

    // ===== drain out[s-1] (scale Sig), update Sig, prefetch x, stage1 =====
    if (s > 0) {
      half8 hr = *(const half8*)&Or_[eidx(dq, dr0)];
      half8 hm = *(const half8*)&Oi_[eidx(dq, dr0)];
      const size_t ob = ((size_t)(s - 1) * NB + b) * 4096 + (size_t)(dq * 64 + dr0);
      float4_t o0, o1, o2, o3;
      #pragma unroll
      for (int e = 0; e < 4; ++e) {
        o0[e] = Sig * (float)hr[e]; o1[e] = Sig * (float)hr[4 + e];
        o2[e] = Sig * (float)hm[e]; o3[e] = Sig * (float)hm[4 + e];
      }
      *(float4_t*)(out + ob) = o0;
      *(float4_t*)(out + ob + 4) = o1;
      *(float4_t*)(out + ob + (size_t)NT * NB * 4096) = o2;
      *(float4_t*)(out + ob + (size_t)NT * NB * 4096 + 4) = o3;
    }
    Sig *= alphainv;  // scale of rv produced by this step's matmuls

    float4_t pa0, pa1, pb0, pb1;
    const bool pf = (s + 1 < NT);
    if (pf) {
      const size_t xb = ((size_t)(s + 1) * NB + b) * 4096 + (size_t)(dq * 64 + dr0);
      pa0 = *(const float4_t*)(data_r + xb);
      pa1 = *(const float4_t*)(data_r + xb + 4);
      pb0 = *(const float4_t*)(data_i + xb);
      pb1 = *(const float4_t*)(data_i + xb + 4);
    }

    // stage1: D1 = v^T * U^T = t^T   (A = V^T from LDS, B = U-frags)
    {
      half8 A0[4], A1[4];
      const int rrow = 32 * rblk + l31;
      #pragma unroll
      for (int kq = 0; kq < 4; ++kq) {
        const int c = 16 * kq + 8 * hi;
        half8 avr = *(const half8*)&Vr[eidx(rrow, c)];
        half8 avi = *(const half8*)&Vi[eidx(rrow, c)];
        if (grp == 0) { A0[kq] = avr; A1[kq] = avi; }   // t_r = Ur vr - Ui vi
        else          { A0[kq] = avi; A1[kq] = avr; }   // t_i = Ur vi + Ui vr
      }
      floatx16 a1h, a1l, a2h, a2l;
      #pragma unroll
      for (int j = 0; j < 16; ++j) { a1h[j] = 0; a1l[j] = 0; a2h[j] = 0; a2l[j] = 0; }
      #pragma unroll
      for (int kq = 0; kq < 4; ++kq) {
        a1h = __builtin_amdgcn_mfma_f32_32x32x16_f16(A0[kq], Urh[kq], a1h, 0, 0, 0);
        a2h = __builtin_amdgcn_mfma_f32_32x32x16_f16(A1[kq], Uih[kq], a2h, 0, 0, 0);
        a1l = __builtin_amdgcn_mfma_f32_32x32x16_f16(A0[kq], Url[kq], a1l, 0, 0, 0);
        a2l = __builtin_amdgcn_mfma_f32_32x32x16_f16(A1[kq], Uil[kq], a2l, 0, 0, 0);
      }
      const float s1 = grp ? 1.0f : -1.0f;
      _Float16* Tg = grp ? Ti : Tr;
      const int tp = 32 * pblk + l31;   // T[p][r] = t[p][r]
      #pragma unroll
      for (int jj = 0; jj < 4; ++jj) {
        const int rr0 = 32 * rblk + 8 * jj + 4 * hi;
        half4_t tv;
        #pragma unroll
        for (int e = 0; e < 4; ++e) {
          const int j = 4 * jj + e;
          tv[e] = (_Float16)((a1h[j] + s1 * a2h[j]) + (a1l[j] + s1 * a2l[j]) * 0.00390625f);
        }
        *(half4_t*)&Tg[eidx(tp, rr0)] = tv;
      }
    }
    if (pf) {  // land x prefetch (latency hidden under stage1 MFMAs)
      half8 hx, hy;
      #pragma unroll
      for (int e = 0; e < 4; ++e) {
        hx[e] = (_Float16)pa0[e]; hx[4 + e] = (_Float16)pa1[e];
        hy[e] = (_Float16)pb0[e]; hy[4 + e] = (_Float16)pb1[e];
      }
      *(half8*)&Xr[eidx(dq, dr0)] = hx;
      *(half8*)&Xi[eidx(dq, dr0)] = hy;
    }
    __syncthreads();  // bar2: T (and X for next iter) published

    // stage2: D2 = U * t^T = h'^T -> rv in registers; publish warp max
    {
      half8 B0[4], B1[4];
      const int p2 = 32 * rblk + l31;
      #pragma unroll
      for (int kq = 0; kq < 4; ++kq) {
        const int c = 16 * kq + 8 * hi;
        half8 btr = *(const half8*)&Tr[eidx(p2, c)];
        half8 bti = *(const half8*)&Ti[eidx(p2, c)];
        if (grp == 0) { B0[kq] = btr; B1[kq] = bti; }   // Re: Ur tr + Ui ti
        else          { B0[kq] = bti; B1[kq] = btr; }   // Im: Ur ti - Ui tr
      }
      floatx16 c1h, c1l, c2h, c2l;
      #pragma unroll
      for (int j = 0; j < 16; ++j) { c1h[j] = 0; c1l[j] = 0; c2h[j] = 0; c2l[j] = 0; }
      #pragma unroll
      for (int kq = 0; kq < 4; ++kq) {
        c1h = __builtin_amdgcn_mfma_f32_32x32x16_f16(Urh[kq], B0[kq], c1h, 0, 0, 0);
        c2h = __builtin_amdgcn_mfma_f32_32x32x16_f16(Uih[kq], B1[kq], c2h, 0, 0, 0);
        c1l = __builtin_amdgcn_mfma_f32_32x32x16_f16(Url[kq], B0[kq], c1l, 0, 0, 0);
        c2l = __builtin_amdgcn_mfma_f32_32x32x16_f16(Uil[kq], B1[kq], c2l, 0, 0, 0);
      }
      const float s2 = grp ? -1.0f : 1.0f;
      float ml = 0.0f;
      #pragma unroll
      for (int j = 0; j < 16; ++j) {
        rv[j] = (c1h[j] + s2 * c2h[j]) + (c1l[j] + s2 * c2l[j]) * 0.00390625f;
        ml = fmaxf(ml, fabsf(rv[j]));
      }
      #pragma unroll
      for (int d = 32; d >= 1; d >>= 1) ml = fmaxf(ml, __shfl_xor(ml, d, 64));
      if (lane == 0) red[w] = ml;
    }
    __syncthreads();  // bar3: red published (fresh alpha for next mix)
  }

  // epilogue: stage + drain out[NT-1] (Sig is the scale of final rv)
  {
    _Float16* Og = grp ? Oi_ : Or_;
    #pragma unroll
    for (int jj = 0; jj < 4; ++jj) {
      const int j0 = 32 * pblk + 8 * jj + 4 * hi;
      half4_t ov;
      #pragma unroll
      for (int e = 0; e < 4; ++e) ov[e] = (_Float16)rv[4 * jj + e];
      *(half4_t*)&Og[eidx(prow, j0)] = ov;
    }
  }
  __syncthreads();
  {
    half8 hr = *(const half8*)&Or_[eidx(dq, dr0)];
    half8 hm = *(const half8*)&Oi_[eidx(dq, dr0)];
    const size_t ob = ((size_t)(NT - 1) * NB + b) * 4096 + (size_t)(dq * 64 + dr0);
    float4_t o0, o1, o2, o3;
    #pragma unroll
    for (int e = 0; e < 4; ++e) {
      o0[e] = Sig * (float)hr[e]; o1[e] = Sig * (float)hr[4 + e];
      o2[e] = Sig * (float)hm[e]; o3[e] = Sig * (float)hm[4 + e];
    }
    *(float4_t*)(out + ob) = o0;
    *(float4_t*)(out + ob + 4) = o1;
    *(float4_t*)(out + ob + (size_t)NT * NB * 4096) = o2;
    *(float4_t*)(out + ob + (size_t)NT * NB * 4096 + 4) = o3;
  }
}

extern "C" void kernel_launch(void* const* d_in, const int* in_sizes, int n_in,
                              void* d_out, int out_size, void* d_ws, size_t ws_size,
                              hipStream_t stream) {
  (void)in_sizes; (void)n_in; (void)out_size; (void)d_ws; (void)ws_size;
  qrnn4<<<dim3(NB), dim3(512), 0, stream>>>(
      (const float*)d_in[0], (const float*)d_in[1],
      (const float*)d_in[2], (const float*)d_in[3],
      (const float*)d_in[4], (float*)d_out);
}

// Round 5
// 418.515 us; speedup vs baseline: 1.1248x; 1.1248x over previous
//
#include <hip/hip_runtime.h>
#include <math.h>

typedef _Float16 half8 __attribute__((ext_vector_type(8)));
typedef _Float16 half4_t __attribute__((ext_vector_type(4)));
typedef float floatx16 __attribute__((ext_vector_type(16)));
typedef float float4_t __attribute__((ext_vector_type(4)));

#define NT 128
#define NB 64

// element index with 8-f16 (16B) unit XOR swizzle inside a 64-f16 (128B) row
__device__ __forceinline__ int eidx(int row, int col) {
  return row * 64 + ((((col >> 3) ^ row) & 7) << 3) + (col & 7);
}

// Barrier draining LDS only (no vmcnt: globals never carry cross-wave data here;
// x: global->reg->LDS with HW scoreboard on the reg; out: write-only).
#define BARX() do {                                        \
  asm volatile("s_waitcnt lgkmcnt(0)" ::: "memory");       \
  __builtin_amdgcn_s_barrier();                            \
  __builtin_amdgcn_sched_barrier(0);                       \
} while (0)

__global__ __launch_bounds__(512, 2)
void qrnn5(const float* __restrict__ data_r, const float* __restrict__ data_i,
           const float* __restrict__ U_r, const float* __restrict__ U_i,
           const float* __restrict__ lam_p, float* __restrict__ out) {
  __shared__ __align__(16) _Float16 Vr[4096], Vi[4096];
  __shared__ __align__(16) _Float16 Tr[4096], Ti[4096];
  __shared__ __align__(16) _Float16 Xr[4096], Xi[4096];
  __shared__ __align__(16) _Float16 Or_[4096], Oi_[4096];
  __shared__ __align__(16) float red[8];

  const int b   = blockIdx.x;
  const int tid = threadIdx.x;
  const int lane = tid & 63;
  const int hi   = lane >> 5;
  const int l31  = lane & 31;
  const int w    = tid >> 6;
  const int grp  = w >> 2;        // 0: real, 1: imag
  const int rblk = (w >> 1) & 1;  // state-row block (stage1 A-row, stage2 B-col)
  const int pblk = w & 1;         // U row block (stage1 B-col, stage2 A-row)

  const float g = 1.0f / (1.0f + expf(-lam_p[0]));

  // U fragments: row = 32*pblk + l31, k = 16*kq + 8*hi + e.
  // Stage1 B-operand (acts as U^T) and stage2 A-operand (acts as U).
  half8 Urh[4], Url[4], Uih[4], Uil[4];
  {
    const int row = 32 * pblk + l31;
    #pragma unroll
    for (int kq = 0; kq < 4; ++kq) {
      const int c0 = 16 * kq + 8 * hi;
      #pragma unroll
      for (int e = 0; e < 8; ++e) {
        const float ur = U_r[row * 64 + c0 + e];
        const float ui = U_i[row * 64 + c0 + e];
        _Float16 h;
        h = (_Float16)ur; Urh[kq][e] = h; Url[kq][e] = (_Float16)((ur - (float)h) * 256.0f);
        h = (_Float16)ui; Uih[kq][e] = h; Uil[kq][e] = (_Float16)((ui - (float)h) * 256.0f);
      }
    }
  }

  // thread state element: h[prow][jcol(j)], jcol(j) = 32*pblk + (j&3) + 8*(j>>2) + 4*hi
  const int prow = 32 * rblk + l31;

  // init: h0_r = I/64, h0_i = 0
  float rv[16];
  #pragma unroll
  for (int j = 0; j < 16; ++j) {
    const int jcol = 32 * pblk + (j & 3) + 8 * (j >> 2) + 4 * hi;
    rv[j] = (grp == 0 && prow == jcol) ? (1.0f / 64.0f) : 0.0f;
  }

  // prologue: x_0 -> X (coalesced f32 loads, f16 staging)
  const int dq = tid >> 3, dr0 = (tid & 7) * 8;
  {
    const size_t xb = (size_t)b * 4096 + (size_t)(dq * 64 + dr0);
    float4_t a0 = *(const float4_t*)(data_r + xb);
    float4_t a1 = *(const float4_t*)(data_r + xb + 4);
    float4_t c0 = *(const float4_t*)(data_i + xb);
    float4_t c1 = *(const float4_t*)(data_i + xb + 4);
    half8 hx, hy;
    #pragma unroll
    for (int e = 0; e < 4; ++e) {
      hx[e] = (_Float16)a0[e]; hx[4 + e] = (_Float16)a1[e];
      hy[e] = (_Float16)c0[e]; hy[4 + e] = (_Float16)c1[e];
    }
    *(half8*)&Xr[eidx(dq, dr0)] = hx;
    *(half8*)&Xi[eidx(dq, dr0)] = hy;
  }
  float Sig = 1.0f, alpha = 1.0f, alphainv = 1.0f;
  BARX();  // X published

  for (int s = 0; s < NT; ++s) {
    // ===== MIX: scale rv by alpha (stale-1), stage V^T + O, publish wave max =====
    {
      const float ga = g * alpha;
      const float kx = (1.0f - g) * alpha / Sig;
      const _Float16* Xg = grp ? Xi : Xr;
      _Float16* Vg = grp ? Vi : Vr;
      _Float16* Og = grp ? Oi_ : Or_;
      #pragma unroll
      for (int jj = 0; jj < 4; ++jj) {
        const int j0 = 32 * pblk + 8 * jj + 4 * hi;
        half4_t xv = *(const half4_t*)&Xg[eidx(prow, j0)];
        half4_t ov;
        #pragma unroll
        for (int e = 0; e < 4; ++e) {
          const float r = rv[4 * jj + e];
          ov[e] = (_Float16)r;
          const float vv = ga * r + kx * (float)xv[e];
          Vg[eidx(j0 + e, prow)] = (_Float16)vv;   // transpose write: V^T
        }
        *(half4_t*)&Og[eidx(prow, j0)] = ov;       // stage raw rv for out drain
      }
      // tree max of |rv| (depth 4) + 6-hop butterfly; only lane0's value used
      float m0[8];
      #pragma unroll
      for (int e = 0; e < 8; ++e) m0[e] = fmaxf(fabsf(rv[e]), fabsf(rv[e + 8]));
      #pragma unroll
      for (int e = 0; e < 4; ++e) m0[e] = fmaxf(m0[e], m0[e + 4]);
      float ml = fmaxf(fmaxf(m0[0], m0[1]), fmaxf(m0[2], m0[3]));
      #pragma unroll
      for (int d = 32; d >= 1; d >>= 1) ml = fmaxf(ml, __shfl_xor(ml, d, 64));
      if (lane == 0) red[w] = ml;
    }
    BARX();  // bar1: V, O, red published

    // ===== REGION2: x prefetch, out drain (Sig_s), alpha update, stage1 =====
    float4_t pa0, pa1, pb0, pb1;
    const bool pf = (s + 1 < NT);
    if (pf) {  // issue earliest: longest latency
      const size_t xb = ((size_t)(s + 1) * NB + b) * 4096 + (size_t)(dq * 64 + dr0);
      pa0 = *(const float4_t*)(data_r + xb);
      pa1 = *(const float4_t*)(data_r + xb + 4);
      pb0 = *(const float4_t*)(data_i + xb);
      pb1 = *(const float4_t*)(data_i + xb + 4);
    }
    if (s > 0) {
      half8 hr = *(const half8*)&Or_[eidx(dq, dr0)];
      half8 hm = *(const half8*)&Oi_[eidx(dq, dr0)];
      const size_t ob = ((size_t)(s - 1) * NB + b) * 4096 + (size_t)(dq * 64 + dr0);
      float4_t o0, o1, o2, o3;
      #pragma unroll
      for (int e = 0; e < 4; ++e) {
        o0[e] = Sig * (float)hr[e]; o1[e] = Sig * (float)hr[4 + e];
        o2[e] = Sig * (float)hm[e]; o3[e] = Sig * (float)hm[4 + e];
      }
      *(float4_t*)(out + ob) = o0;
      *(float4_t*)(out + ob + 4) = o1;
      *(float4_t*)(out + ob + (size_t)NT * NB * 4096) = o2;
      *(float4_t*)(out + ob + (size_t)NT * NB * 4096 + 4) = o3;
    }
    Sig *= alphainv;  // Sig_{s+1}: scale of rv produced by this step's matmuls
    {
      float4_t r0 = *(const float4_t*)&red[0];
      float4_t r1 = *(const float4_t*)&red[4];
      float mm = fmaxf(fmaxf(fmaxf(r0[0], r0[1]), fmaxf(r0[2], r0[3])),
                       fmaxf(fmaxf(r1[0], r1[1]), fmaxf(r1[2], r1[3])));
      int E = 0;
      if (mm > 0.0f) frexpf(mm, &E);
      alpha = ldexpf(1.0f, -E);   // for next mix (stale-1)
      alphainv = ldexpf(1.0f, E);
    }

    // stage1: D1 = v^T * U^T = t^T   (A = V^T from LDS, B = U-frags)
    {
      half8 A0[4], A1[4];
      const int rrow = 32 * rblk + l31;
      #pragma unroll
      for (int kq = 0; kq < 4; ++kq) {
        const int c = 16 * kq + 8 * hi;
        half8 avr = *(const half8*)&Vr[eidx(rrow, c)];
        half8 avi = *(const half8*)&Vi[eidx(rrow, c)];
        if (grp == 0) { A0[kq] = avr; A1[kq] = avi; }   // t_r = Ur vr - Ui vi
        else          { A0[kq] = avi; A1[kq] = avr; }   // t_i = Ur vi + Ui vr
      }
      floatx16 a1h, a1l, a2h, a2l;
      #pragma unroll
      for (int j = 0; j < 16; ++j) { a1h[j] = 0; a1l[j] = 0; a2h[j] = 0; a2l[j] = 0; }
      #pragma unroll
      for (int kq = 0; kq < 4; ++kq) {
        a1h = __builtin_amdgcn_mfma_f32_32x32x16_f16(A0[kq], Urh[kq], a1h, 0, 0, 0);
        a2h = __builtin_amdgcn_mfma_f32_32x32x16_f16(A1[kq], Uih[kq], a2h, 0, 0, 0);
        a1l = __builtin_amdgcn_mfma_f32_32x32x16_f16(A0[kq], Url[kq], a1l, 0, 0, 0);
        a2l = __builtin_amdgcn_mfma_f32_32x32x16_f16(A1[kq], Uil[kq], a2l, 0, 0, 0);
      }
      const float s1 = grp ? 1.0f : -1.0f;
      _Float16* Tg = grp ? Ti : Tr;
      const int tp = 32 * pblk + l31;   // T[p][r] = t[p][r]
      #pragma unroll
      for (int jj = 0; jj < 4; ++jj) {
        const int rr0 = 32 * rblk + 8 * jj + 4 * hi;
        half4_t tv;
        #pragma unroll
        for (int e = 0; e < 4; ++e) {
          const int j = 4 * jj + e;
          tv[e] = (_Float16)((a1h[j] + s1 * a2h[j]) + (a1l[j] + s1 * a2l[j]) * 0.00390625f);
        }
        *(half4_t*)&Tg[eidx(tp, rr0)] = tv;
      }
    }
    if (pf) {  // land x prefetch (vmcnt scoreboard wait hidden under stage1 MFMAs)
      half8 hx, hy;
      #pragma unroll
      for (int e = 0; e < 4; ++e) {
        hx[e] = (_Float16)pa0[e]; hx[4 + e] = (_Float16)pa1[e];
        hy[e] = (_Float16)pb0[e]; hy[4 + e] = (_Float16)pb1[e];
      }
      *(half8*)&Xr[eidx(dq, dr0)] = hx;
      *(half8*)&Xi[eidx(dq, dr0)] = hy;
    }
    BARX();  // bar2: T (and X for next iter) published

    // stage2: D2 = U * t^T = h'^T -> rv stays in registers
    {
      half8 B0[4], B1[4];
      const int p2 = 32 * rblk + l31;
      #pragma unroll
      for (int kq = 0; kq < 4; ++kq) {
        const int c = 16 * kq + 8 * hi;
        half8 btr = *(const half8*)&Tr[eidx(p2, c)];
        half8 bti = *(const half8*)&Ti[eidx(p2, c)];
        if (grp == 0) { B0[kq] = btr; B1[kq] = bti; }   // Re: Ur tr + Ui ti
        else          { B0[kq] = bti; B1[kq] = btr; }   // Im: Ur ti - Ui tr
      }
      floatx16 c1h, c1l, c2h, c2l;
      #pragma unroll
      for (int j = 0; j < 16; ++j) { c1h[j] = 0; c1l[j] = 0; c2h[j] = 0; c2l[j] = 0; }
      #pragma unroll
      for (int kq = 0; kq < 4; ++kq) {
        c1h = __builtin_amdgcn_mfma_f32_32x32x16_f16(Urh[kq], B0[kq], c1h, 0, 0, 0);
        c2h = __builtin_amdgcn_mfma_f32_32x32x16_f16(Uih[kq], B1[kq], c2h, 0, 0, 0);
        c1l = __builtin_amdgcn_mfma_f32_32x32x16_f16(Url[kq], B0[kq], c1l, 0, 0, 0);
        c2l = __builtin_amdgcn_mfma_f32_32x32x16_f16(Uil[kq], B1[kq], c2l, 0, 0, 0);
      }
      const float s2 = grp ? -1.0f : 1.0f;
      #pragma unroll
      for (int j = 0; j < 16; ++j)
        rv[j] = (c1h[j] + s2 * c2h[j]) + (c1l[j] + s2 * c2l[j]) * 0.00390625f;
    }
    // no barrier here: stage2(s) and mix(s+1) touch disjoint LDS (T vs V/O/red/X-read)
  }

  // epilogue: stage + drain out[NT-1] (Sig = Sig_NT, scale of final rv)
  {
    _Float16* Og = grp ? Oi_ : Or_;
    #pragma unroll
    for (int jj = 0; jj < 4; ++jj) {
      const int j0 = 32 * pblk + 8 * jj + 4 * hi;
      half4_t ov;
      #pragma unroll
      for (int e = 0; e < 4; ++e) ov[e] = (_Float16)rv[4 * jj + e];
      *(half4_t*)&Og[eidx(prow, j0)] = ov;
    }
  }
  BARX();
  {
    half8 hr = *(const half8*)&Or_[eidx(dq, dr0)];
    half8 hm = *(const half8*)&Oi_[eidx(dq, dr0)];
    const size_t ob = ((size_t)(NT - 1) * NB + b) * 4096 + (size_t)(dq * 64 + dr0);
    float4_t o0, o1, o2, o3;
    #pragma unroll
    for (int e = 0; e < 4; ++e) {
      o0[e] = Sig * (float)hr[e]; o1[e] = Sig * (float)hr[4 + e];
      o2[e] = Sig * (float)hm[e]; o3[e] = Sig * (float)hm[4 + e];
    }
    *(float4_t*)(out + ob) = o0;
    *(float4_t*)(out + ob + 4) = o1;
    *(float4_t*)(out + ob + (size_t)NT * NB * 4096) = o2;
    *(float4_t*)(out + ob + (size_t)NT * NB * 4096 + 4) = o3;
  }
}

extern "C" void kernel_launch(void* const* d_in, const int* in_sizes, int n_in,
                              void* d_out, int out_size, void* d_ws, size_t ws_size,
                              hipStream_t stream) {
  (void)in_sizes; (void)n_in; (void)out_size; (void)d_ws; (void)ws_size;
  qrnn5<<<dim3(NB), dim3(512), 0, stream>>>(
      (const float*)d_in[0], (const float*)d_in[1],
      (const float*)d_in[2], (const float*)d_in[3],
      (const float*)d_in[4], (float*)d_out);
}

// Round 6
// 299.033 us; speedup vs baseline: 1.5742x; 1.3996x over previous
//
#include <hip/hip_runtime.h>
#include <math.h>

typedef _Float16 half8 __attribute__((ext_vector_type(8)));
typedef _Float16 half4_t __attribute__((ext_vector_type(4)));
typedef float floatx16 __attribute__((ext_vector_type(16)));
typedef float float4_t __attribute__((ext_vector_type(4)));

#define NT 128
#define NB 64
#define NC 8
#define CL 16

// element index with 8-f16 (16B) unit XOR swizzle inside a 64-f16 (128B) row
__device__ __forceinline__ int eidx(int row, int col) {
  return row * 64 + ((((col >> 3) ^ row) & 7) << 3) + (col & 7);
}
__device__ __forceinline__ int jcolf(int j, int pblk, int hi) {
  return 32 * pblk + (j & 3) + 8 * (j >> 2) + 4 * hi;
}

// LDS-only barrier (globals never carry intra-kernel cross-wave data here)
#define BARX() do {                                        \
  asm volatile("s_waitcnt lgkmcnt(0)" ::: "memory");       \
  __builtin_amdgcn_s_barrier();                            \
  __builtin_amdgcn_sched_barrier(0);                       \
} while (0)

// ---------------- chunk scan: PASS3=false -> emit p_c ; PASS3=true -> emit out ----
template<bool PASS3>
__global__ __launch_bounds__(512, 2)
void qrnn_scan(const float* __restrict__ data_r, const float* __restrict__ data_i,
               const float* __restrict__ U_r, const float* __restrict__ U_i,
               const float* __restrict__ lam_p, float* __restrict__ out) {
  __shared__ __align__(16) _Float16 Vr[4096], Vi[4096];
  __shared__ __align__(16) _Float16 Tr[4096], Ti[4096];
  __shared__ __align__(16) _Float16 Xr[4096], Xi[4096];
  __shared__ __align__(16) _Float16 Or_[4096], Oi_[4096];
  __shared__ __align__(16) float red[8];

  const int bx = blockIdx.x;
  const int b  = bx & (NB - 1);
  const int c  = bx >> 6;          // chunk id 0..7
  const int t0 = c * CL;
  const int tid = threadIdx.x;
  const int lane = tid & 63, hi = lane >> 5, l31 = lane & 31, w = tid >> 6;
  const int grp = w >> 2, rblk = (w >> 1) & 1, pblk = w & 1;
  const int prow = 32 * rblk + l31;

  const float g = 1.0f / (1.0f + expf(-lam_p[0]));

  // U fragments (hi + lo*256)
  half8 Urh[4], Url[4], Uih[4], Uil[4];
  {
    const int row = 32 * pblk + l31;
    #pragma unroll
    for (int kq = 0; kq < 4; ++kq) {
      const int c0 = 16 * kq + 8 * hi;
      #pragma unroll
      for (int e = 0; e < 8; ++e) {
        const float ur = U_r[row * 64 + c0 + e];
        const float ui = U_i[row * 64 + c0 + e];
        _Float16 h;
        h = (_Float16)ur; Urh[kq][e] = h; Url[kq][e] = (_Float16)((ur - (float)h) * 256.0f);
        h = (_Float16)ui; Uih[kq][e] = h; Uil[kq][e] = (_Float16)((ui - (float)h) * 256.0f);
      }
    }
  }

  // ---- initial state ----
  float rv[16];
  if constexpr (PASS3) {
    if (c == 0) {
      #pragma unroll
      for (int j = 0; j < 16; ++j)
        rv[j] = (grp == 0 && prow == jcolf(j, pblk, hi)) ? (1.0f / 64.0f) : 0.0f;
    } else {
      const float* hs = out + ((size_t)((grp ? NT : 0) + t0 + 1) * NB + b) * 4096;
      #pragma unroll
      for (int j = 0; j < 16; ++j)
        rv[j] = hs[prow * 64 + jcolf(j, pblk, hi)];
    }
  } else {
    #pragma unroll
    for (int j = 0; j < 16; ++j) rv[j] = 0.0f;
  }
  // block max of |rv| -> entry normalization
  {
    float ml = 0.0f;
    #pragma unroll
    for (int j = 0; j < 16; ++j) ml = fmaxf(ml, fabsf(rv[j]));
    #pragma unroll
    for (int d = 32; d >= 1; d >>= 1) ml = fmaxf(ml, __shfl_xor(ml, d, 64));
    if (lane == 0) red[w] = ml;
  }

  // stage x_{t0} -> X
  const int dq = tid >> 3, dr0 = (tid & 7) * 8;
  {
    const size_t xb = ((size_t)t0 * NB + b) * 4096 + (size_t)(dq * 64 + dr0);
    float4_t a0 = *(const float4_t*)(data_r + xb);
    float4_t a1 = *(const float4_t*)(data_r + xb + 4);
    float4_t c0 = *(const float4_t*)(data_i + xb);
    float4_t c1 = *(const float4_t*)(data_i + xb + 4);
    half8 hx, hy;
    #pragma unroll
    for (int e = 0; e < 4; ++e) {
      hx[e] = (_Float16)a0[e]; hx[4 + e] = (_Float16)a1[e];
      hy[e] = (_Float16)c0[e]; hy[4 + e] = (_Float16)c1[e];
    }
    *(half8*)&Xr[eidx(dq, dr0)] = hx;
    *(half8*)&Xi[eidx(dq, dr0)] = hy;
  }
  BARX();  // X + red published

  float Sig, alpha = 1.0f, alphainv = 1.0f;
  {
    float4_t r0 = *(const float4_t*)&red[0];
    float4_t r1 = *(const float4_t*)&red[4];
    float mm = fmaxf(fmaxf(fmaxf(r0[0], r0[1]), fmaxf(r0[2], r0[3])),
                     fmaxf(fmaxf(r1[0], r1[1]), fmaxf(r1[2], r1[3])));
    int E0 = 0;
    if (mm > 0.0f) frexpf(mm, &E0);
    const float sc = ldexpf(1.0f, -E0);
    #pragma unroll
    for (int j = 0; j < 16; ++j) rv[j] *= sc;   // normalize entry state
    Sig = ldexpf(1.0f, E0);                     // true h = Sig * rv
  }

  for (int s = 0; s < CL; ++s) {
    // ===== MIX =====
    {
      const float ga = g * alpha;
      const float kx = (1.0f - g) * alpha / Sig;
      const _Float16* Xg = grp ? Xi : Xr;
      _Float16* Vg = grp ? Vi : Vr;
      #pragma unroll
      for (int jj = 0; jj < 4; ++jj) {
        const int j0 = 32 * pblk + 8 * jj + 4 * hi;
        half4_t xv = *(const half4_t*)&Xg[eidx(prow, j0)];
        #pragma unroll
        for (int e = 0; e < 4; ++e) {
          const float r = rv[4 * jj + e];
          const float vv = ga * r + kx * (float)xv[e];
          Vg[eidx(j0 + e, prow)] = (_Float16)vv;   // V^T
        }
      }
      if constexpr (PASS3) {  // stage O = alpha*rv (normalized band, f16-safe)
        _Float16* Og = grp ? Oi_ : Or_;
        #pragma unroll
        for (int jj = 0; jj < 4; ++jj) {
          const int j0 = 32 * pblk + 8 * jj + 4 * hi;
          half4_t ov;
          #pragma unroll
          for (int e = 0; e < 4; ++e) ov[e] = (_Float16)(alpha * rv[4 * jj + e]);
          *(half4_t*)&Og[eidx(prow, j0)] = ov;
        }
      }
      float m0[8];
      #pragma unroll
      for (int e = 0; e < 8; ++e) m0[e] = fmaxf(fabsf(rv[e]), fabsf(rv[e + 8]));
      #pragma unroll
      for (int e = 0; e < 4; ++e) m0[e] = fmaxf(m0[e], m0[e + 4]);
      float ml = fmaxf(fmaxf(m0[0], m0[1]), fmaxf(m0[2], m0[3]));
      #pragma unroll
      for (int d = 32; d >= 1; d >>= 1) ml = fmaxf(ml, __shfl_xor(ml, d, 64));
      if (lane == 0) red[w] = ml;
    }
    BARX();  // bar1: V, O, red published

    // ===== REGION2 =====
    float4_t pa0, pa1, pb0, pb1;
    const bool pf = (s + 1 < CL);
    if (pf) {
      const size_t xb = ((size_t)(t0 + s + 1) * NB + b) * 4096 + (size_t)(dq * 64 + dr0);
      pa0 = *(const float4_t*)(data_r + xb);
      pa1 = *(const float4_t*)(data_r + xb + 4);
      pb0 = *(const float4_t*)(data_i + xb);
      pb1 = *(const float4_t*)(data_i + xb + 4);
    }
    Sig *= alphainv;  // Sig now = true scale of staged O and of upcoming stage2 rv
    if constexpr (PASS3) {
      if (s > 0) {
        half8 hr = *(const half8*)&Or_[eidx(dq, dr0)];
        half8 hm = *(const half8*)&Oi_[eidx(dq, dr0)];
        float* oR = out + ((size_t)(t0 + s - 1) * NB + b) * 4096 + (size_t)(dq * 64 + dr0);
        float4_t o0, o1, o2, o3;
        #pragma unroll
        for (int e = 0; e < 4; ++e) {
          o0[e] = Sig * (float)hr[e]; o1[e] = Sig * (float)hr[4 + e];
          o2[e] = Sig * (float)hm[e]; o3[e] = Sig * (float)hm[4 + e];
        }
        *(float4_t*)(oR) = o0;
        *(float4_t*)(oR + 4) = o1;
        *(float4_t*)(oR + (size_t)NT * NB * 4096) = o2;
        *(float4_t*)(oR + (size_t)NT * NB * 4096 + 4) = o3;
      }
    }
    {
      float4_t r0 = *(const float4_t*)&red[0];
      float4_t r1 = *(const float4_t*)&red[4];
      float mm = fmaxf(fmaxf(fmaxf(r0[0], r0[1]), fmaxf(r0[2], r0[3])),
                       fmaxf(fmaxf(r1[0], r1[1]), fmaxf(r1[2], r1[3])));
      int E = 0;
      if (mm > 0.0f) frexpf(mm, &E);
      alpha = ldexpf(1.0f, -E);   // for next mix (stale-1)
      alphainv = ldexpf(1.0f, E);
    }

    // stage1: t^T = V^T * U^T
    {
      half8 A0[4], A1[4];
      const int rrow = 32 * rblk + l31;
      #pragma unroll
      for (int kq = 0; kq < 4; ++kq) {
        const int cc = 16 * kq + 8 * hi;
        half8 avr = *(const half8*)&Vr[eidx(rrow, cc)];
        half8 avi = *(const half8*)&Vi[eidx(rrow, cc)];
        if (grp == 0) { A0[kq] = avr; A1[kq] = avi; }
        else          { A0[kq] = avi; A1[kq] = avr; }
      }
      floatx16 a1h, a1l, a2h, a2l;
      #pragma unroll
      for (int j = 0; j < 16; ++j) { a1h[j] = 0; a1l[j] = 0; a2h[j] = 0; a2l[j] = 0; }
      #pragma unroll
      for (int kq = 0; kq < 4; ++kq) {
        a1h = __builtin_amdgcn_mfma_f32_32x32x16_f16(A0[kq], Urh[kq], a1h, 0, 0, 0);
        a2h = __builtin_amdgcn_mfma_f32_32x32x16_f16(A1[kq], Uih[kq], a2h, 0, 0, 0);
        a1l = __builtin_amdgcn_mfma_f32_32x32x16_f16(A0[kq], Url[kq], a1l, 0, 0, 0);
        a2l = __builtin_amdgcn_mfma_f32_32x32x16_f16(A1[kq], Uil[kq], a2l, 0, 0, 0);
      }
      const float s1 = grp ? 1.0f : -1.0f;
      _Float16* Tg = grp ? Ti : Tr;
      const int tp = 32 * pblk + l31;
      #pragma unroll
      for (int jj = 0; jj < 4; ++jj) {
        const int rr0 = 32 * rblk + 8 * jj + 4 * hi;
        half4_t tv;
        #pragma unroll
        for (int e = 0; e < 4; ++e) {
          const int j = 4 * jj + e;
          tv[e] = (_Float16)((a1h[j] + s1 * a2h[j]) + (a1l[j] + s1 * a2l[j]) * 0.00390625f);
        }
        *(half4_t*)&Tg[eidx(tp, rr0)] = tv;
      }
    }
    if (pf) {
      half8 hx, hy;
      #pragma unroll
      for (int e = 0; e < 4; ++e) {
        hx[e] = (_Float16)pa0[e]; hx[4 + e] = (_Float16)pa1[e];
        hy[e] = (_Float16)pb0[e]; hy[4 + e] = (_Float16)pb1[e];
      }
      *(half8*)&Xr[eidx(dq, dr0)] = hx;
      *(half8*)&Xi[eidx(dq, dr0)] = hy;
    }
    BARX();  // bar2: T (and X for next iter) published

    // stage2: h'^T = U * t^T -> rv
    {
      half8 B0[4], B1[4];
      const int p2 = 32 * rblk + l31;
      #pragma unroll
      for (int kq = 0; kq < 4; ++kq) {
        const int cc = 16 * kq + 8 * hi;
        half8 btr = *(const half8*)&Tr[eidx(p2, cc)];
        half8 bti = *(const half8*)&Ti[eidx(p2, cc)];
        if (grp == 0) { B0[kq] = btr; B1[kq] = bti; }
        else          { B0[kq] = bti; B1[kq] = btr; }
      }
      floatx16 c1h, c1l, c2h, c2l;
      #pragma unroll
      for (int j = 0; j < 16; ++j) { c1h[j] = 0; c1l[j] = 0; c2h[j] = 0; c2l[j] = 0; }
      #pragma unroll
      for (int kq = 0; kq < 4; ++kq) {
        c1h = __builtin_amdgcn_mfma_f32_32x32x16_f16(Urh[kq], B0[kq], c1h, 0, 0, 0);
        c2h = __builtin_amdgcn_mfma_f32_32x32x16_f16(Uih[kq], B1[kq], c2h, 0, 0, 0);
        c1l = __builtin_amdgcn_mfma_f32_32x32x16_f16(Url[kq], B0[kq], c1l, 0, 0, 0);
        c2l = __builtin_amdgcn_mfma_f32_32x32x16_f16(Uil[kq], B1[kq], c2l, 0, 0, 0);
      }
      const float s2 = grp ? -1.0f : 1.0f;
      #pragma unroll
      for (int j = 0; j < 16; ++j)
        rv[j] = (c1h[j] + s2 * c2h[j]) + (c1l[j] + s2 * c2l[j]) * 0.00390625f;
    }
  }

  // ---- epilogue: PASS3 -> out[t0+CL-1] ; PASS1 -> p_c slot (out row t0) ----
  {
    _Float16* Og = grp ? Oi_ : Or_;
    #pragma unroll
    for (int jj = 0; jj < 4; ++jj) {
      const int j0 = 32 * pblk + 8 * jj + 4 * hi;
      half4_t ov;
      #pragma unroll
      for (int e = 0; e < 4; ++e) ov[e] = (_Float16)rv[4 * jj + e];
      *(half4_t*)&Og[eidx(prow, j0)] = ov;
    }
  }
  BARX();
  {
    const int trow = PASS3 ? (t0 + CL - 1) : t0;
    float* eR = out + ((size_t)trow * NB + b) * 4096 + (size_t)(dq * 64 + dr0);
    half8 hr = *(const half8*)&Or_[eidx(dq, dr0)];
    half8 hm = *(const half8*)&Oi_[eidx(dq, dr0)];
    float4_t o0, o1, o2, o3;
    #pragma unroll
    for (int e = 0; e < 4; ++e) {
      o0[e] = Sig * (float)hr[e]; o1[e] = Sig * (float)hr[4 + e];
      o2[e] = Sig * (float)hm[e]; o3[e] = Sig * (float)hm[4 + e];
    }
    *(float4_t*)(eR) = o0;
    *(float4_t*)(eR + 4) = o1;
    *(float4_t*)(eR + (size_t)NT * NB * 4096) = o2;
    *(float4_t*)(eR + (size_t)NT * NB * 4096 + 4) = o3;
  }
}

// ---------------- K2: W = U^16 (4 LDS squarings) + 7 sequential chunk combines ----
__global__ __launch_bounds__(512, 1)
void qrnn_combine(const float* __restrict__ U_r, const float* __restrict__ U_i,
                  const float* __restrict__ lam_p, float* __restrict__ out) {
  __shared__ float Ga_r[64 * 68], Ga_i[64 * 68], Gb_r[64 * 68], Gb_i[64 * 68];
  __shared__ __align__(16) _Float16 Vr[4096], Vi[4096], Tr[4096], Ti[4096];
  __shared__ float red[8];

  const int b = blockIdx.x;
  const int tid = threadIdx.x;
  const int lane = tid & 63, hi = lane >> 5, l31 = lane & 31, w = tid >> 6;
  const int grp = w >> 2, rblk = (w >> 1) & 1, pblk = w & 1;
  const int prow = 32 * rblk + l31;

  const float g = 1.0f / (1.0f + expf(-lam_p[0]));
  const float g2 = g * g, g4 = g2 * g2, g8 = g4 * g4, g16 = g8 * g8;

  // load U -> Ga
  const int qr = tid >> 3, qc = (tid & 7) * 8;
  {
    *(float4_t*)&Ga_r[qr * 68 + qc]     = *(const float4_t*)(U_r + qr * 64 + qc);
    *(float4_t*)&Ga_r[qr * 68 + qc + 4] = *(const float4_t*)(U_r + qr * 64 + qc + 4);
    *(float4_t*)&Ga_i[qr * 68 + qc]     = *(const float4_t*)(U_i + qr * 64 + qc);
    *(float4_t*)&Ga_i[qr * 68 + qc + 4] = *(const float4_t*)(U_i + qr * 64 + qc + 4);
  }
  __syncthreads();

  // 4 squarings: Ga->Gb->Ga->Gb->Ga   (W = U^16 ends in Ga)
  #pragma unroll
  for (int it = 0; it < 4; ++it) {
    const float* sr = (it & 1) ? Gb_r : Ga_r;
    const float* si = (it & 1) ? Gb_i : Ga_i;
    float* dr = (it & 1) ? Ga_r : Gb_r;
    float* di = (it & 1) ? Ga_i : Gb_i;
    float cr[8], ci[8];
    #pragma unroll
    for (int e = 0; e < 8; ++e) { cr[e] = 0.0f; ci[e] = 0.0f; }
    for (int k = 0; k < 64; ++k) {
      const float ar = sr[qr * 68 + k];
      const float ai = si[qr * 68 + k];
      float4_t br0 = *(const float4_t*)&sr[k * 68 + qc];
      float4_t br1 = *(const float4_t*)&sr[k * 68 + qc + 4];
      float4_t bi0 = *(const float4_t*)&si[k * 68 + qc];
      float4_t bi1 = *(const float4_t*)&si[k * 68 + qc + 4];
      #pragma unroll
      for (int e = 0; e < 4; ++e) {
        cr[e]     += ar * br0[e] - ai * bi0[e];
        ci[e]     += ar * bi0[e] + ai * br0[e];
        cr[4 + e] += ar * br1[e] - ai * bi1[e];
        ci[4 + e] += ar * bi1[e] + ai * br1[e];
      }
    }
    float4_t s0, s1, s2, s3;
    #pragma unroll
    for (int e = 0; e < 4; ++e) { s0[e] = cr[e]; s1[e] = cr[4 + e]; s2[e] = ci[e]; s3[e] = ci[4 + e]; }
    *(float4_t*)&dr[qr * 68 + qc] = s0;  *(float4_t*)&dr[qr * 68 + qc + 4] = s1;
    *(float4_t*)&di[qr * 68 + qc] = s2;  *(float4_t*)&di[qr * 68 + qc + 4] = s3;
    __syncthreads();
  }

  // extract W frags (hi + lo*256)
  half8 Wrh[4], Wrl[4], Wih[4], Wil[4];
  {
    const int row = 32 * pblk + l31;
    #pragma unroll
    for (int kq = 0; kq < 4; ++kq) {
      const int c0 = 16 * kq + 8 * hi;
      #pragma unroll
      for (int e = 0; e < 8; ++e) {
        const float wr = Ga_r[row * 68 + c0 + e];
        const float wi = Ga_i[row * 68 + c0 + e];
        _Float16 h;
        h = (_Float16)wr; Wrh[kq][e] = h; Wrl[kq][e] = (_Float16)((wr - (float)h) * 256.0f);
        h = (_Float16)wi; Wih[kq][e] = h; Wil[kq][e] = (_Float16)((wi - (float)h) * 256.0f);
      }
    }
  }

  // H = h0
  float rv[16];
  #pragma unroll
  for (int j = 0; j < 16; ++j)
    rv[j] = (grp == 0 && prow == jcolf(j, pblk, hi)) ? (1.0f / 64.0f) : 0.0f;

  for (int c = 0; c < NC - 1; ++c) {
    // p_c loads (raw f32, out row t=16c)
    float pv[16];
    {
      const float* ps = out + ((size_t)((grp ? NT : 0) + c * CL) * NB + b) * 4096;
      #pragma unroll
      for (int j = 0; j < 16; ++j) pv[j] = ps[prow * 64 + jcolf(j, pblk, hi)];
    }
    // fresh alpha from |rv|
    float ml = 0.0f;
    #pragma unroll
    for (int j = 0; j < 16; ++j) ml = fmaxf(ml, fabsf(rv[j]));
    #pragma unroll
    for (int d = 32; d >= 1; d >>= 1) ml = fmaxf(ml, __shfl_xor(ml, d, 64));
    if (lane == 0) red[w] = ml;
    __syncthreads();
    float mm = red[0];
    #pragma unroll
    for (int i = 1; i < 8; ++i) mm = fmaxf(mm, red[i]);
    int E = 0;
    if (mm > 0.0f) frexpf(mm, &E);
    const float al = ldexpf(1.0f, -E);
    const float fE = g16 * ldexpf(1.0f, E);

    // V^T = al * H
    {
      _Float16* Vg = grp ? Vi : Vr;
      #pragma unroll
      for (int j = 0; j < 16; ++j)
        Vg[eidx(jcolf(j, pblk, hi), prow)] = (_Float16)(al * rv[j]);
    }
    __syncthreads();

    // stage1: T = (W (al H))^T-path
    {
      half8 A0[4], A1[4];
      const int rrow = 32 * rblk + l31;
      #pragma unroll
      for (int kq = 0; kq < 4; ++kq) {
        const int cc = 16 * kq + 8 * hi;
        half8 avr = *(const half8*)&Vr[eidx(rrow, cc)];
        half8 avi = *(const half8*)&Vi[eidx(rrow, cc)];
        if (grp == 0) { A0[kq] = avr; A1[kq] = avi; }
        else          { A0[kq] = avi; A1[kq] = avr; }
      }
      floatx16 a1h, a1l, a2h, a2l;
      #pragma unroll
      for (int j = 0; j < 16; ++j) { a1h[j] = 0; a1l[j] = 0; a2h[j] = 0; a2l[j] = 0; }
      #pragma unroll
      for (int kq = 0; kq < 4; ++kq) {
        a1h = __builtin_amdgcn_mfma_f32_32x32x16_f16(A0[kq], Wrh[kq], a1h, 0, 0, 0);
        a2h = __builtin_amdgcn_mfma_f32_32x32x16_f16(A1[kq], Wih[kq], a2h, 0, 0, 0);
        a1l = __builtin_amdgcn_mfma_f32_32x32x16_f16(A0[kq], Wrl[kq], a1l, 0, 0, 0);
        a2l = __builtin_amdgcn_mfma_f32_32x32x16_f16(A1[kq], Wil[kq], a2l, 0, 0, 0);
      }
      const float s1 = grp ? 1.0f : -1.0f;
      _Float16* Tg = grp ? Ti : Tr;
      const int tp = 32 * pblk + l31;
      #pragma unroll
      for (int jj = 0; jj < 4; ++jj) {
        const int rr0 = 32 * rblk + 8 * jj + 4 * hi;
        half4_t tv;
        #pragma unroll
        for (int e = 0; e < 4; ++e) {
          const int j = 4 * jj + e;
          tv[e] = (_Float16)((a1h[j] + s1 * a2h[j]) + (a1l[j] + s1 * a2l[j]) * 0.00390625f);
        }
        *(half4_t*)&Tg[eidx(tp, rr0)] = tv;
      }
    }
    __syncthreads();

    // stage2 -> rvS ; H = g16*2^E*rvS + p_c
    {
      half8 B0[4], B1[4];
      const int p2 = 32 * rblk + l31;
      #pragma unroll
      for (int kq = 0; kq < 4; ++kq) {
        const int cc = 16 * kq + 8 * hi;
        half8 btr = *(const half8*)&Tr[eidx(p2, cc)];
        half8 bti = *(const half8*)&Ti[eidx(p2, cc)];
        if (grp == 0) { B0[kq] = btr; B1[kq] = bti; }
        else          { B0[kq] = bti; B1[kq] = btr; }
      }
      floatx16 c1h, c1l, c2h, c2l;
      #pragma unroll
      for (int j = 0; j < 16; ++j) { c1h[j] = 0; c1l[j] = 0; c2h[j] = 0; c2l[j] = 0; }
      #pragma unroll
      for (int kq = 0; kq < 4; ++kq) {
        c1h = __builtin_amdgcn_mfma_f32_32x32x16_f16(Wrh[kq], B0[kq], c1h, 0, 0, 0);
        c2h = __builtin_amdgcn_mfma_f32_32x32x16_f16(Wih[kq], B1[kq], c2h, 0, 0, 0);
        c1l = __builtin_amdgcn_mfma_f32_32x32x16_f16(Wrl[kq], B0[kq], c1l, 0, 0, 0);
        c2l = __builtin_amdgcn_mfma_f32_32x32x16_f16(Wil[kq], B1[kq], c2l, 0, 0, 0);
      }
      const float s2 = grp ? -1.0f : 1.0f;
      #pragma unroll
      for (int j = 0; j < 16; ++j) {
        const float rvS = (c1h[j] + s2 * c2h[j]) + (c1l[j] + s2 * c2l[j]) * 0.00390625f;
        rv[j] = fE * rvS + pv[j];
      }
    }
    // write H_start(c+1) to out row t=16(c+1)+1 (raw f32)
    {
      float* hs = out + ((size_t)((grp ? NT : 0) + (c + 1) * CL + 1) * NB + b) * 4096;
      #pragma unroll
      for (int j = 0; j < 16; ++j) hs[prow * 64 + jcolf(j, pblk, hi)] = rv[j];
    }
    __syncthreads();
  }
}

extern "C" void kernel_launch(void* const* d_in, const int* in_sizes, int n_in,
                              void* d_out, int out_size, void* d_ws, size_t ws_size,
                              hipStream_t stream) {
  (void)in_sizes; (void)n_in; (void)out_size; (void)d_ws; (void)ws_size;
  const float* dr = (const float*)d_in[0];
  const float* di = (const float*)d_in[1];
  const float* ur = (const float*)d_in[2];
  const float* ui = (const float*)d_in[3];
  const float* lm = (const float*)d_in[4];
  float* o = (float*)d_out;
  qrnn_scan<false><<<dim3(NB * NC), dim3(512), 0, stream>>>(dr, di, ur, ui, lm, o);
  qrnn_combine<<<dim3(NB), dim3(512), 0, stream>>>(ur, ui, lm, o);
  qrnn_scan<true><<<dim3(NB * NC), dim3(512), 0, stream>>>(dr, di, ur, ui, lm, o);
}